// Round 1
// baseline (816.355 us; speedup 1.0000x reference)
//
#include <hip/hip_runtime.h>
#include <stdint.h>

#define N_KERNELS 10000
#define T_LEN 1024
#define HALO_Q 5
#define LDS_PER_BC 1264      // floats per (b,c): worst case d=16 -> 16*79=1264
#define NBLK 1266            // >= sum_g ceil(size_g/8) worst case (<=1263)
#define RNG_STEPS 160        // 64 lanes * 160 next64 = 20480 u32 draws >= 20000

typedef unsigned __int128 u128;

// ---------------------------------------------------------------------------
// Kernel A: replicate numpy default_rng(0) -> SeedSequence(0) -> PCG64,
// Generator.integers(0,3,10000) then integers(0,5,10000) via 32-bit Lemire.
// Each lane jumps the LCG ahead lane*RNG_STEPS steps and emits its slice.
// ---------------------------------------------------------------------------
__global__ void rng_kernel(int* __restrict__ karr, int* __restrict__ darr) {
    const u128 MULT = (((u128)0x2360ED051FC65DA4ULL) << 64) | 0x4385DF649FCCF645ULL;

    // --- SeedSequence(0): pool mixing (all lanes compute identically) ---
    uint32_t hc = 0x43b0d7e5u;                    // INIT_A
    auto hashmix = [&hc](uint32_t v) -> uint32_t {
        v ^= hc; hc *= 0x931e8875u;               // MULT_A
        v *= hc; v ^= v >> 16; return v;
    };
    uint32_t pool[4];
    pool[0] = hashmix(0u);   // entropy word 0 (seed = 0)
    pool[1] = hashmix(0u);
    pool[2] = hashmix(0u);
    pool[3] = hashmix(0u);
    for (int s = 0; s < 4; s++)
        for (int dd = 0; dd < 4; dd++)
            if (s != dd) {
                uint32_t hv = hashmix(pool[s]);
                uint32_t rr = 0xca01f9ddu * pool[dd] - 0x4973f715u * hv;  // MIX_L,MIX_R
                rr ^= rr >> 16;
                pool[dd] = rr;
            }
    // generate_state(4, uint64) -> 8 uint32 words
    uint32_t st[8];
    uint32_t hcb = 0x8b51f9ddu;                   // INIT_B
    for (int i = 0; i < 8; i++) {
        uint32_t dv = pool[i & 3];
        dv ^= hcb; hcb *= 0x58f38dedu;            // MULT_B
        dv *= hcb; dv ^= dv >> 16;
        st[i] = dv;
    }
    // little-endian uint32 pairs -> uint64; seed[0]/inc[0] are HIGH words
    uint64_t w0 = (uint64_t)st[0] | ((uint64_t)st[1] << 32);
    uint64_t w1 = (uint64_t)st[2] | ((uint64_t)st[3] << 32);
    uint64_t w2 = (uint64_t)st[4] | ((uint64_t)st[5] << 32);
    uint64_t w3 = (uint64_t)st[6] | ((uint64_t)st[7] << 32);
    u128 initstate = (((u128)w0) << 64) | w1;
    u128 initseq   = (((u128)w2) << 64) | w3;

    // pcg_setseq_128_srandom_r
    u128 inc   = (initseq << 1) | 1;
    u128 state = 0;
    state = state * MULT + inc;
    state += initstate;
    state = state * MULT + inc;

    // --- per-lane jump-ahead by lane*RNG_STEPS steps ---
    int lane = threadIdx.x;
    u128 Ae = 1, Ce = 0, Ab = MULT, Cb = inc;
    unsigned e = (unsigned)(lane * RNG_STEPS);
    while (e) {
        if (e & 1u) { Ae = Ab * Ae; Ce = Ab * Ce + Cb; }
        Cb = Ab * Cb + Cb;
        Ab = Ab * Ab;
        e >>= 1;
    }
    u128 s = Ae * state + Ce;

    int base = lane * (2 * RNG_STEPS);   // u32 draw index of this lane's first draw
    for (int t = 0; t < RNG_STEPS; t++) {
        s = s * MULT + inc;              // step, then XSL-RR output of NEW state
        uint64_t hi = (uint64_t)(s >> 64), lo = (uint64_t)s;
        unsigned rot = (unsigned)(hi >> 58);
        uint64_t v = hi ^ lo;
        uint64_t o = (v >> rot) | (v << ((64u - rot) & 63u));
        uint32_t d0 = (uint32_t)o;            // next_uint32 returns LOW half first
        uint32_t d1 = (uint32_t)(o >> 32);
        int i0 = base + 2 * t;
        if (i0 < 10000)       karr[i0] = (int)(((uint64_t)d0 * 3u) >> 32);
        else if (i0 < 20000)  darr[i0 - 10000] = (int)(((uint64_t)d0 * 5u) >> 32);
        int i1 = i0 + 1;
        if (i1 < 10000)       karr[i1] = (int)(((uint64_t)d1 * 3u) >> 32);
        else if (i1 < 20000)  darr[i1 - 10000] = (int)(((uint64_t)d1 * 5u) >> 32);
    }
}

// ---------------------------------------------------------------------------
// Kernel B: bucket kernels by (k,d) group, build per-block schedule:
// sched[bi*10 + 0]=k, +1=log2(d), +2..+9 = 8 kernel ids (padded w/ last; -1 = dead)
// ---------------------------------------------------------------------------
__global__ void sched_kernel(const int* __restrict__ karr, const int* __restrict__ darr,
                             int* __restrict__ list, int* __restrict__ sched) {
    __shared__ int cnt[16], off[16], cur[16], bcnt[16], boff[16];
    int tid = threadIdx.x;
    if (tid < 16) cnt[tid] = 0;
    __syncthreads();
    for (int i = tid; i < N_KERNELS; i += 256) {
        int g = karr[i] * 5 + darr[i];
        atomicAdd(&cnt[g], 1);
    }
    __syncthreads();
    if (tid == 0) {
        int o = 0, bo = 0;
        for (int g = 0; g < 15; g++) {
            off[g] = o;  o += cnt[g];
            boff[g] = bo; bcnt[g] = (cnt[g] + 7) / 8; bo += bcnt[g];
        }
        off[15] = o; boff[15] = bo;
    }
    __syncthreads();
    if (tid < 16) cur[tid] = 0;
    __syncthreads();
    for (int i = tid; i < N_KERNELS; i += 256) {
        int g = karr[i] * 5 + darr[i];
        int p = atomicAdd(&cur[g], 1);
        list[off[g] + p] = i;
    }
    __syncthreads();
    int totalb = boff[15];
    const int kv[3] = {7, 9, 11};
    for (int bi = tid; bi < NBLK; bi += 256) {
        int* sp = sched + bi * 10;
        int g = -1;
        if (bi < totalb) {
            for (int gg = 0; gg < 15; gg++)
                if (bi >= boff[gg] && bi < boff[gg] + bcnt[gg]) { g = gg; break; }
        }
        if (g < 0) { sp[0] = 7; sp[1] = 0; sp[2] = -1; continue; }
        int chunk  = bi - boff[g];
        int bstart = off[g] + chunk * 8;
        int glast  = off[g] + cnt[g] - 1;
        sp[0] = kv[g / 5];
        sp[1] = g % 5;                       // DILS={1,2,4,8,16} -> index == log2(d)
        for (int j = 0; j < 8; j++) {
            int ii = bstart + j;
            sp[2 + j] = list[ii <= glast ? ii : glast];
        }
    }
}

// ---------------------------------------------------------------------------
// Kernel C: main compute. One block = 8 same-(k,d) kernels x 64 batches.
// x staged in LDS de-interleaved by dilation residue with swizzle s+(s>>4).
// ---------------------------------------------------------------------------
template <int K>
__device__ __forceinline__ void body(const float* __restrict__ x,
                                     const float* __restrict__ wgt,
                                     const float* __restrict__ bias,
                                     const int* __restrict__ sp,
                                     float* __restrict__ out,
                                     float (&lds)[4][3][LDS_PER_BC],
                                     int ld2) {
    const int tid = threadIdx.x;
    const int d = 1 << ld2;
    const int Q = T_LEN >> ld2;
    const int L = Q + 11;                 // always odd
    const int pitch2 = L + (L >> 4);      // swizzled row pitch (odd)
    const int h = (K - 1) / 2;

    // zero all of LDS once (halos must be 0; staging overwrites data slots)
    float* lf = &lds[0][0][0];
    for (int i = tid; i < 4 * 3 * LDS_PER_BC; i += 256) lf[i] = 0.f;

    const int tile = tid & 63;
    const int bsub = tid >> 6;            // wave id == batch sub-index
    const int r  = tile >> (6 - ld2);     // dilation residue
    const int tq = tile & ((64 >> ld2) - 1);
    const int q0 = tq << 4;
    const int rbase = r * pitch2;
    const int sbase = (HALO_Q - h) + q0;

    for (int b0 = 0; b0 < 64; b0 += 4) {
        __syncthreads();                  // covers zeroing on iter 0, prev reads later
        // ---- stage 4 batches: 3072 float4, de-interleave by residue ----
        #pragma unroll
        for (int m = 0; m < 12; m++) {
            int f4 = tid + 256 * m;
            int bo = f4 / 768;
            int rem = f4 - bo * 768;
            int c = rem >> 8;
            int p4 = rem & 255;
            float4 xv = reinterpret_cast<const float4*>(x)[((b0 + bo) * 3 + c) * 256 + p4];
            int p = p4 << 2;
            float* dst = &lds[bo][c][0];
            int pe, rr, qq, ss;
            pe = p;     rr = pe & (d - 1); qq = pe >> ld2; ss = HALO_Q + qq; dst[rr * pitch2 + ss + (ss >> 4)] = xv.x;
            pe = p + 1; rr = pe & (d - 1); qq = pe >> ld2; ss = HALO_Q + qq; dst[rr * pitch2 + ss + (ss >> 4)] = xv.y;
            pe = p + 2; rr = pe & (d - 1); qq = pe >> ld2; ss = HALO_Q + qq; dst[rr * pitch2 + ss + (ss >> 4)] = xv.z;
            pe = p + 3; rr = pe & (d - 1); qq = pe >> ld2; ss = HALO_Q + qq; dst[rr * pitch2 + ss + (ss >> 4)] = xv.w;
        }
        __syncthreads();

        // ---- load this thread's x-window into registers ----
        float xw[3][15 + K];
        #pragma unroll
        for (int c = 0; c < 3; c++) {
            const float* src = &lds[bsub][c][0] + rbase;
            #pragma unroll
            for (int i2 = 0; i2 < 15 + K; i2++) {
                int ssw = sbase + i2;
                xw[c][i2] = src[ssw + (ssw >> 4)];
            }
        }

        const int b = b0 + bsub;
        float* outb = out + (size_t)b * (2 * N_KERNELS);

        // ---- 8 kernels sharing the staged windows ----
        #pragma unroll 1
        for (int g = 0; g < 8; g++) {
            int n = sp[2 + g];
            const float* wp = wgt + n * 33;
            float acc[16];
            #pragma unroll
            for (int i = 0; i < 16; i++) acc[i] = 0.f;
            #pragma unroll
            for (int c = 0; c < 3; c++) {
                #pragma unroll
                for (int j = 0; j < K; j++) {
                    float wv = wp[c * 11 + j];
                    #pragma unroll
                    for (int i = 0; i < 16; i++)
                        acc[i] = fmaf(wv, xw[c][i + j], acc[i]);
                }
            }
            float bv = bias[n];
            float mx = -3.402823466e38f;
            int cp = 0;
            #pragma unroll
            for (int i = 0; i < 16; i++) {
                float v = acc[i] + bv;
                mx = fmaxf(mx, v);
                cp += (v > 0.f) ? 1 : 0;
            }
            #pragma unroll
            for (int o = 32; o > 0; o >>= 1) {
                mx = fmaxf(mx, __shfl_down(mx, o));
                cp += __shfl_down(cp, o);
            }
            if (tile == 0) {
                float2 res = make_float2(mx, (float)cp * (1.0f / 1024.0f));
                *reinterpret_cast<float2*>(outb + 2 * n) = res;
            }
        }
    }
}

__global__ __launch_bounds__(256, 2)
void rocket_main(const float* __restrict__ x, const float* __restrict__ wgt,
                 const float* __restrict__ bias, const int* __restrict__ sched,
                 float* __restrict__ out) {
    __shared__ float lds[4][3][LDS_PER_BC];   // 60.7 KB
    const int* sp = sched + blockIdx.x * 10;
    if (sp[2] < 0) return;                    // dead (padding) block — uniform exit
    int K = sp[0], ld2 = sp[1];
    if (K == 7)       body<7>(x, wgt, bias, sp, out, lds, ld2);
    else if (K == 9)  body<9>(x, wgt, bias, sp, out, lds, ld2);
    else              body<11>(x, wgt, bias, sp, out, lds, ld2);
}

extern "C" void kernel_launch(void* const* d_in, const int* in_sizes, int n_in,
                              void* d_out, int out_size, void* d_ws, size_t ws_size,
                              hipStream_t stream) {
    const float* x   = (const float*)d_in[0];
    const float* w   = (const float*)d_in[1];
    const float* b   = (const float*)d_in[2];
    float* out = (float*)d_out;

    int* wsi  = (int*)d_ws;
    int* karr = wsi;            // 10000
    int* darr = wsi + 10000;    // 10000
    int* list = wsi + 20000;    // 10000
    int* schd = wsi + 30000;    // NBLK*10 = 12660  -> ~171 KB total ws use

    hipLaunchKernelGGL(rng_kernel,   dim3(1),    dim3(64),  0, stream, karr, darr);
    hipLaunchKernelGGL(sched_kernel, dim3(1),    dim3(256), 0, stream, karr, darr, list, schd);
    hipLaunchKernelGGL(rocket_main,  dim3(NBLK), dim3(256), 0, stream, x, w, b, schd, out);
}